// Round 4
// baseline (263.729 us; speedup 1.0000x reference)
//
#include <hip/hip_runtime.h>

// TinyRNN fused kernel for MI355X (gfx950).
// Mapping: 16 lanes (= one DPP row) per batch element; lane j owns h[j] (j<12,
// lanes 12..15 are zero-pad). The 12x12 recurrent matvec is done with 16
// row_ror DPP rotations, each FMA'd against a per-lane pre-permuted W_hh entry.
// No LDS, no __syncthreads, no cross-wave traffic. 4096 batches * 16 lanes =
// 65536 threads = 1024 waves = 1 wave per SIMD across the whole chip.

#if __has_builtin(__builtin_amdgcn_exp2f)
#define EXP2F(v) __builtin_amdgcn_exp2f(v)
#else
#define EXP2F(v) exp2f(v)
#endif

#if __has_builtin(__builtin_amdgcn_rcpf)
#define RCPF(v) __builtin_amdgcn_rcpf(v)
#else
#define RCPF(v) (1.0f / (v))
#endif

template <int N>
__device__ __forceinline__ float rot16(float v) {
    // ROW_ROR:N within the 16-lane DPP row. All 64 lanes are always active in
    // the main loop, so every rotation source is valid.
    int s = __builtin_bit_cast(int, v);
    int r = __builtin_amdgcn_update_dpp(0, s, 0x120 + N, 0xF, 0xF, true);
    return __builtin_bit_cast(float, r);
}

#define TRNN_T 2048
#define TRNN_H 12

// One RNN step. 4 independent FMA chains (c0..c3) to shorten the dependence
// path; tanh(a) = 1 - 2/(exp2(a*2*log2e)+1) -> v_exp_f32 + v_rcp_f32.
#define STEP(XT) { \
    float c0 = fmaf((XT), wih, bias); \
    c0 = fmaf(h, wr[0], c0); \
    float c1 = rot16<1>(h) * wr[1]; \
    float c2 = rot16<2>(h) * wr[2]; \
    float c3 = rot16<3>(h) * wr[3]; \
    c0 = fmaf(rot16<4>(h),  wr[4],  c0); \
    c1 = fmaf(rot16<5>(h),  wr[5],  c1); \
    c2 = fmaf(rot16<6>(h),  wr[6],  c2); \
    c3 = fmaf(rot16<7>(h),  wr[7],  c3); \
    c0 = fmaf(rot16<8>(h),  wr[8],  c0); \
    c1 = fmaf(rot16<9>(h),  wr[9],  c1); \
    c2 = fmaf(rot16<10>(h), wr[10], c2); \
    c3 = fmaf(rot16<11>(h), wr[11], c3); \
    c0 = fmaf(rot16<12>(h), wr[12], c0); \
    c1 = fmaf(rot16<13>(h), wr[13], c1); \
    c2 = fmaf(rot16<14>(h), wr[14], c2); \
    c3 = fmaf(rot16<15>(h), wr[15], c3); \
    float aa = (c0 + c1) + (c2 + c3); \
    float tt = EXP2F(aa * 2.8853900817779268f); \
    h = fmaf(-2.0f, RCPF(tt + 1.0f), 1.0f); \
}

#define STEP4(F4) STEP((F4).x) STEP((F4).y) STEP((F4).z) STEP((F4).w)

__global__ __launch_bounds__(256, 1) void tinyrnn_kernel(
    const float* __restrict__ x,
    const float* __restrict__ W_ih,
    const float* __restrict__ W_hh,
    const float* __restrict__ b_ih,
    const float* __restrict__ b_hh,
    const float* __restrict__ W_head,
    const float* __restrict__ b_head,
    float* __restrict__ out)
{
    const int tid = blockIdx.x * 256 + threadIdx.x;
    const int b   = tid >> 4;   // batch element
    const int j   = tid & 15;   // hidden unit (12..15 = pad), == lane position in DPP row

    // Runtime probe of ROW_ROR direction: recv = (j +/- 1) & 15. d in {1,15}.
    // Weight permutation below is then correct regardless of HW convention.
    const int recv = __builtin_amdgcn_update_dpp(0, j, 0x121, 0xF, 0xF, true);
    const int d    = (recv - j) & 15;

    // Per-lane pre-permuted recurrent weights: rotation r delivers h[(j+d*r)&15],
    // so pair it with W_hh[j][(j+d*r)&15]; zero for pad rows/cols.
    float wr[16];
#pragma unroll
    for (int r = 0; r < 16; ++r) {
        const int k = (j + d * r) & 15;
        wr[r] = (j < TRNN_H && k < TRNN_H) ? W_hh[j * TRNN_H + k] : 0.0f;
    }
    const float wih  = (j < TRNN_H) ? W_ih[j] : 0.0f;                       // I == 1
    const float bias = (j < TRNN_H) ? (b_ih[j] + b_hh[j]) : 0.0f;
    const float wh0  = (j < TRNN_H) ? W_head[j] : 0.0f;                     // O == 2
    const float wh1  = (j < TRNN_H) ? W_head[TRNN_H + j] : 0.0f;

    // All 16 lanes of a group load the same x addresses (coalesce to one
    // transaction per group). Double-buffered 16-step (4 x float4) chunks,
    // issued one full 16-step block (~900 cyc) ahead of use.
    const float4* __restrict__ xb = (const float4*)(x + (size_t)b * TRNN_T);

    float h = 0.0f;
    float4 A0 = xb[0], A1 = xb[1], A2 = xb[2], A3 = xb[3];
    float4 B0, B1, B2, B3;

    for (int tc = 0; tc < TRNN_T; tc += 32) {
        const int c = tc >> 2;
        B0 = xb[c + 4]; B1 = xb[c + 5]; B2 = xb[c + 6]; B3 = xb[c + 7];
        STEP4(A0) STEP4(A1) STEP4(A2) STEP4(A3)
        if (tc + 32 < TRNN_T) {
            A0 = xb[c + 8]; A1 = xb[c + 9]; A2 = xb[c + 10]; A3 = xb[c + 11];
        }
        STEP4(B0) STEP4(B1) STEP4(B2) STEP4(B3)
    }

    // Head: out[b][o] = sum_j h[j]*W_head[o][j] + b_head[o]; 16-lane xor-reduce.
    float p0 = h * wh0;
    float p1 = h * wh1;
#pragma unroll
    for (int m = 8; m >= 1; m >>= 1) {
        p0 += __shfl_xor(p0, m, 16);
        p1 += __shfl_xor(p1, m, 16);
    }
    if (j == 0) {
        out[2 * b]     = p0 + b_head[0];
        out[2 * b + 1] = p1 + b_head[1];
    }
}

extern "C" void kernel_launch(void* const* d_in, const int* in_sizes, int n_in,
                              void* d_out, int out_size, void* d_ws, size_t ws_size,
                              hipStream_t stream) {
    const float* x      = (const float*)d_in[0];
    const float* W_ih   = (const float*)d_in[1];
    const float* W_hh   = (const float*)d_in[2];
    const float* b_ih   = (const float*)d_in[3];
    const float* b_hh   = (const float*)d_in[4];
    const float* W_head = (const float*)d_in[5];
    const float* b_head = (const float*)d_in[6];
    float* out = (float*)d_out;

    const int B = in_sizes[0] / TRNN_T;           // 4096
    dim3 grid((unsigned)(B * 16 / 256));          // 256 blocks
    dim3 block(256);                              // 4 waves/block -> 1 wave/SIMD
    tinyrnn_kernel<<<grid, block, 0, stream>>>(x, W_ih, W_hh, b_ih, b_hh,
                                               W_head, b_head, out);
}

// Round 5
// 206.250 us; speedup vs baseline: 1.2787x; 1.2787x over previous
//
#include <hip/hip_runtime.h>

// TinyRNN fused kernel for MI355X (gfx950) — round 5.
// Mapping: 16 lanes (= one DPP row) per batch element; lane j owns h[j] (j<12,
// lanes 12..15 zero-pad). The 12x12 recurrent matvec = 16 v_fmac_f32/v_mul_f32
// with row_ror DPP on src0 (inline asm — the compiler never folds
// update_dpp movs into FMAs; round-4 profile showed ~80 VALU instr/step from
// the unfused movs + zero-inits, 246 cyc/step).
// The tanh input scale 2*log2(e) is pre-folded into W_hh/W_ih/biases
// (linearity), removing the serial v_mul before v_exp_f32.
// 4096 batches * 16 lanes = 65536 threads = 1024 waves = 1 wave/SIMD chip-wide.

#if __has_builtin(__builtin_amdgcn_exp2f)
#define EXP2F(v) __builtin_amdgcn_exp2f(v)
#else
#define EXP2F(v) exp2f(v)
#endif

#if __has_builtin(__builtin_amdgcn_rcpf)
#define RCPF(v) __builtin_amdgcn_rcpf(v)
#else
#define RCPF(v) (1.0f / (v))
#endif

#define TRNN_T 2048
#define TRNN_H 12

// One RNN step. Seed fma (x-term, off the h-chain) in C; 16-op matvec in one
// asm block: 4 independent accumulator chains, DPP row_ror on src0 delivers
// h[(j+d*r)&15] to lane j, paired with pre-permuted pre-scaled wr[r].
// Then aa = 2*log2e*(Wh+wx+b) already scaled -> tanh = 1 - 2/(exp2(aa)+1).
#define STEP(XT) { \
    float c0 = fmaf((XT), wih, bias); \
    float c1, c2, c3; \
    asm("v_fmac_f32 %0, %4, %5\n\t" \
        "v_mul_f32 %1, %4, %6 row_ror:1\n\t" \
        "v_mul_f32 %2, %4, %7 row_ror:2\n\t" \
        "v_mul_f32 %3, %4, %8 row_ror:3\n\t" \
        "v_fmac_f32 %0, %4, %9 row_ror:4\n\t" \
        "v_fmac_f32 %1, %4, %10 row_ror:5\n\t" \
        "v_fmac_f32 %2, %4, %11 row_ror:6\n\t" \
        "v_fmac_f32 %3, %4, %12 row_ror:7\n\t" \
        "v_fmac_f32 %0, %4, %13 row_ror:8\n\t" \
        "v_fmac_f32 %1, %4, %14 row_ror:9\n\t" \
        "v_fmac_f32 %2, %4, %15 row_ror:10\n\t" \
        "v_fmac_f32 %3, %4, %16 row_ror:11\n\t" \
        "v_fmac_f32 %0, %4, %17 row_ror:12\n\t" \
        "v_fmac_f32 %1, %4, %18 row_ror:13\n\t" \
        "v_fmac_f32 %2, %4, %19 row_ror:14\n\t" \
        "v_fmac_f32 %3, %4, %20 row_ror:15" \
        : "+v"(c0), "=&v"(c1), "=&v"(c2), "=&v"(c3) \
        : "v"(h), "v"(wr[0]), "v"(wr[1]), "v"(wr[2]), "v"(wr[3]), \
          "v"(wr[4]), "v"(wr[5]), "v"(wr[6]), "v"(wr[7]), \
          "v"(wr[8]), "v"(wr[9]), "v"(wr[10]), "v"(wr[11]), \
          "v"(wr[12]), "v"(wr[13]), "v"(wr[14]), "v"(wr[15])); \
    float aa = (c0 + c1) + (c2 + c3); \
    float tt = EXP2F(aa); \
    h = fmaf(-2.0f, RCPF(tt + 1.0f), 1.0f); \
}

#define STEP4(F4) STEP((F4).x) STEP((F4).y) STEP((F4).z) STEP((F4).w)

__global__ __launch_bounds__(256, 1) void tinyrnn_kernel(
    const float* __restrict__ x,
    const float* __restrict__ W_ih,
    const float* __restrict__ W_hh,
    const float* __restrict__ b_ih,
    const float* __restrict__ b_hh,
    const float* __restrict__ W_head,
    const float* __restrict__ b_head,
    float* __restrict__ out)
{
    const int tid = blockIdx.x * 256 + threadIdx.x;
    const int b   = tid >> 4;   // batch element
    const int j   = tid & 15;   // hidden unit (12..15 = pad) == DPP row position

    // Runtime probe of ROW_ROR direction (same HW op as the asm row_ror):
    // recv = (j +/- 1) & 15, d in {1,15}. Weight permutation built from d is
    // correct regardless of the HW receive-from convention.
    const int recv = __builtin_amdgcn_update_dpp(0, j, 0x121, 0xF, 0xF, true);
    const int d    = (recv - j) & 15;

    // Pre-permuted, pre-scaled recurrent weights: rotation r delivers
    // h[(j+d*r)&15] -> pair with S*W_hh[j][(j+d*r)&15]; zero pad rows/cols.
    const float S = 2.8853900817779268f;   // 2*log2(e), folds tanh scale
    float wr[16];
#pragma unroll
    for (int r = 0; r < 16; ++r) {
        const int k = (j + d * r) & 15;
        wr[r] = (j < TRNN_H && k < TRNN_H) ? W_hh[j * TRNN_H + k] * S : 0.0f;
    }
    const float wih  = (j < TRNN_H) ? W_ih[j] * S : 0.0f;                   // I == 1
    const float bias = (j < TRNN_H) ? (b_ih[j] + b_hh[j]) * S : 0.0f;
    const float wh0  = (j < TRNN_H) ? W_head[j] : 0.0f;                     // O == 2
    const float wh1  = (j < TRNN_H) ? W_head[TRNN_H + j] : 0.0f;

    // All 16 lanes of a group load the same x addresses. Double-buffered
    // 16-step (4 x float4) chunks issued a full 16-step block ahead of use.
    const float4* __restrict__ xb = (const float4*)(x + (size_t)b * TRNN_T);

    float h = 0.0f;
    float4 A0 = xb[0], A1 = xb[1], A2 = xb[2], A3 = xb[3];
    float4 B0, B1, B2, B3;

    for (int tc = 0; tc < TRNN_T; tc += 32) {
        const int c = tc >> 2;
        B0 = xb[c + 4]; B1 = xb[c + 5]; B2 = xb[c + 6]; B3 = xb[c + 7];
        STEP4(A0) STEP4(A1) STEP4(A2) STEP4(A3)
        if (tc + 32 < TRNN_T) {
            A0 = xb[c + 8]; A1 = xb[c + 9]; A2 = xb[c + 10]; A3 = xb[c + 11];
        }
        STEP4(B0) STEP4(B1) STEP4(B2) STEP4(B3)
    }

    // Head: out[b][o] = sum_j h[j]*W_head[o][j] + b_head[o]; 16-lane xor-reduce.
    float p0 = h * wh0;
    float p1 = h * wh1;
#pragma unroll
    for (int m = 8; m >= 1; m >>= 1) {
        p0 += __shfl_xor(p0, m, 16);
        p1 += __shfl_xor(p1, m, 16);
    }
    if (j == 0) {
        out[2 * b]     = p0 + b_head[0];
        out[2 * b + 1] = p1 + b_head[1];
    }
}

extern "C" void kernel_launch(void* const* d_in, const int* in_sizes, int n_in,
                              void* d_out, int out_size, void* d_ws, size_t ws_size,
                              hipStream_t stream) {
    const float* x      = (const float*)d_in[0];
    const float* W_ih   = (const float*)d_in[1];
    const float* W_hh   = (const float*)d_in[2];
    const float* b_ih   = (const float*)d_in[3];
    const float* b_hh   = (const float*)d_in[4];
    const float* W_head = (const float*)d_in[5];
    const float* b_head = (const float*)d_in[6];
    float* out = (float*)d_out;

    const int B = in_sizes[0] / TRNN_T;           // 4096
    dim3 grid((unsigned)(B * 16 / 256));          // 256 blocks
    dim3 block(256);                              // 4 waves/block -> 1 wave/SIMD
    tinyrnn_kernel<<<grid, block, 0, stream>>>(x, W_ih, W_hh, b_ih, b_hh,
                                               W_head, b_head, out);
}

// Round 6
// 186.849 us; speedup vs baseline: 1.4115x; 1.1038x over previous
//
#include <hip/hip_runtime.h>

// TinyRNN fused kernel for MI355X (gfx950) — round 6.
// Round-5 post-mortem: VGPR_Count=32 proved the compiler sank the x-prefetch
// loads next to their uses (8 float4 buffers alone need 32 VGPRs), exposing
// L2/HBM latency every ~4 steps (~69 stall cyc/step = 172 total vs 103 issue).
// Fix: __builtin_amdgcn_sched_barrier(0) after each load group pins the loads
// a full 16 steps (~2700 cyc) ahead of first use; RA must keep buffers live.
// Also peeled the last iteration (removes the per-iteration uniform branch).
//
// Mapping unchanged: 16 lanes (one DPP row) per batch; lane j owns h[j]
// (12..15 pad). 12x12 matvec = 16 v_fmac/v_mul row_ror DPP ops (inline asm),
// tanh scale 2*log2(e) pre-folded into weights; tanh = 1 - 2/(exp2(aa)+1).
// 4096 batches * 16 lanes = 65536 threads = 1024 waves = 1 wave/SIMD.

#if __has_builtin(__builtin_amdgcn_exp2f)
#define EXP2F(v) __builtin_amdgcn_exp2f(v)
#else
#define EXP2F(v) exp2f(v)
#endif

#if __has_builtin(__builtin_amdgcn_rcpf)
#define RCPF(v) __builtin_amdgcn_rcpf(v)
#else
#define RCPF(v) (1.0f / (v))
#endif

#define TRNN_T 2048
#define TRNN_H 12

// One RNN step. Seed fma (x-term, off the h-chain); 16-op DPP matvec in one
// asm block (4 independent accumulator chains); then tanh via exp2+rcp.
#define STEP(XT) { \
    float c0 = fmaf((XT), wih, bias); \
    float c1, c2, c3; \
    asm("v_fmac_f32 %0, %4, %5\n\t" \
        "v_mul_f32 %1, %4, %6 row_ror:1\n\t" \
        "v_mul_f32 %2, %4, %7 row_ror:2\n\t" \
        "v_mul_f32 %3, %4, %8 row_ror:3\n\t" \
        "v_fmac_f32 %0, %4, %9 row_ror:4\n\t" \
        "v_fmac_f32 %1, %4, %10 row_ror:5\n\t" \
        "v_fmac_f32 %2, %4, %11 row_ror:6\n\t" \
        "v_fmac_f32 %3, %4, %12 row_ror:7\n\t" \
        "v_fmac_f32 %0, %4, %13 row_ror:8\n\t" \
        "v_fmac_f32 %1, %4, %14 row_ror:9\n\t" \
        "v_fmac_f32 %2, %4, %15 row_ror:10\n\t" \
        "v_fmac_f32 %3, %4, %16 row_ror:11\n\t" \
        "v_fmac_f32 %0, %4, %17 row_ror:12\n\t" \
        "v_fmac_f32 %1, %4, %18 row_ror:13\n\t" \
        "v_fmac_f32 %2, %4, %19 row_ror:14\n\t" \
        "v_fmac_f32 %3, %4, %20 row_ror:15" \
        : "+v"(c0), "=&v"(c1), "=&v"(c2), "=&v"(c3) \
        : "v"(h), "v"(wr[0]), "v"(wr[1]), "v"(wr[2]), "v"(wr[3]), \
          "v"(wr[4]), "v"(wr[5]), "v"(wr[6]), "v"(wr[7]), \
          "v"(wr[8]), "v"(wr[9]), "v"(wr[10]), "v"(wr[11]), \
          "v"(wr[12]), "v"(wr[13]), "v"(wr[14]), "v"(wr[15])); \
    float aa = (c0 + c1) + (c2 + c3); \
    float tt = EXP2F(aa); \
    h = fmaf(-2.0f, RCPF(tt + 1.0f), 1.0f); \
}

#define STEP4(F4) STEP((F4).x) STEP((F4).y) STEP((F4).z) STEP((F4).w)

__global__ __launch_bounds__(256, 1) void tinyrnn_kernel(
    const float* __restrict__ x,
    const float* __restrict__ W_ih,
    const float* __restrict__ W_hh,
    const float* __restrict__ b_ih,
    const float* __restrict__ b_hh,
    const float* __restrict__ W_head,
    const float* __restrict__ b_head,
    float* __restrict__ out)
{
    const int tid = blockIdx.x * 256 + threadIdx.x;
    const int b   = tid >> 4;   // batch element
    const int j   = tid & 15;   // hidden unit (12..15 = pad) == DPP row position

    // Runtime probe of ROW_ROR direction (same HW op as the asm row_ror):
    // recv = (j +/- 1) & 15, d in {1,15}; weight permutation built from d is
    // correct regardless of the HW receive-from convention.
    const int recv = __builtin_amdgcn_update_dpp(0, j, 0x121, 0xF, 0xF, true);
    const int d    = (recv - j) & 15;

    // Pre-permuted, pre-scaled recurrent weights: rotation r delivers
    // h[(j+d*r)&15] -> pair with S*W_hh[j][(j+d*r)&15]; zero pad rows/cols.
    const float S = 2.8853900817779268f;   // 2*log2(e), folds tanh scale
    float wr[16];
#pragma unroll
    for (int r = 0; r < 16; ++r) {
        const int k = (j + d * r) & 15;
        wr[r] = (j < TRNN_H && k < TRNN_H) ? W_hh[j * TRNN_H + k] * S : 0.0f;
    }
    const float wih  = (j < TRNN_H) ? W_ih[j] * S : 0.0f;                   // I == 1
    const float bias = (j < TRNN_H) ? (b_ih[j] + b_hh[j]) * S : 0.0f;
    const float wh0  = (j < TRNN_H) ? W_head[j] : 0.0f;                     // O == 2
    const float wh1  = (j < TRNN_H) ? W_head[TRNN_H + j] : 0.0f;

    // All 16 lanes of a group load the same x addresses. Double-buffered
    // 16-step (4 x float4) chunks; sched_barrier(0) pins each load group so
    // the scheduler cannot sink it into the dependent STEP4 blocks.
    const float4* __restrict__ xb = (const float4*)(x + (size_t)b * TRNN_T);

    float h = 0.0f;
    float4 A0 = xb[0], A1 = xb[1], A2 = xb[2], A3 = xb[3];
    float4 B0, B1, B2, B3;
    __builtin_amdgcn_sched_barrier(0);

    int tc;
    for (tc = 0; tc < TRNN_T - 32; tc += 32) {
        const int c = tc >> 2;
        B0 = xb[c + 4]; B1 = xb[c + 5]; B2 = xb[c + 6]; B3 = xb[c + 7];
        __builtin_amdgcn_sched_barrier(0);
        STEP4(A0) STEP4(A1) STEP4(A2) STEP4(A3)
        A0 = xb[c + 8]; A1 = xb[c + 9]; A2 = xb[c + 10]; A3 = xb[c + 11];
        __builtin_amdgcn_sched_barrier(0);
        STEP4(B0) STEP4(B1) STEP4(B2) STEP4(B3)
    }
    // Peeled final 32 steps (tc == TRNN_T-32): no A-reload.
    {
        const int c = tc >> 2;
        B0 = xb[c + 4]; B1 = xb[c + 5]; B2 = xb[c + 6]; B3 = xb[c + 7];
        __builtin_amdgcn_sched_barrier(0);
        STEP4(A0) STEP4(A1) STEP4(A2) STEP4(A3)
        STEP4(B0) STEP4(B1) STEP4(B2) STEP4(B3)
    }

    // Head: out[b][o] = sum_j h[j]*W_head[o][j] + b_head[o]; 16-lane xor-reduce.
    float p0 = h * wh0;
    float p1 = h * wh1;
#pragma unroll
    for (int m = 8; m >= 1; m >>= 1) {
        p0 += __shfl_xor(p0, m, 16);
        p1 += __shfl_xor(p1, m, 16);
    }
    if (j == 0) {
        out[2 * b]     = p0 + b_head[0];
        out[2 * b + 1] = p1 + b_head[1];
    }
}

extern "C" void kernel_launch(void* const* d_in, const int* in_sizes, int n_in,
                              void* d_out, int out_size, void* d_ws, size_t ws_size,
                              hipStream_t stream) {
    const float* x      = (const float*)d_in[0];
    const float* W_ih   = (const float*)d_in[1];
    const float* W_hh   = (const float*)d_in[2];
    const float* b_ih   = (const float*)d_in[3];
    const float* b_hh   = (const float*)d_in[4];
    const float* W_head = (const float*)d_in[5];
    const float* b_head = (const float*)d_in[6];
    float* out = (float*)d_out;

    const int B = in_sizes[0] / TRNN_T;           // 4096
    dim3 grid((unsigned)(B * 16 / 256));          // 256 blocks
    dim3 block(256);                              // 4 waves/block -> 1 wave/SIMD
    tinyrnn_kernel<<<grid, block, 0, stream>>>(x, W_ih, W_hh, b_ih, b_hh,
                                               W_head, b_head, out);
}